// Round 3
// baseline (279.601 us; speedup 1.0000x reference)
//
#include <hip/hip_runtime.h>
#include <hip/hip_bf16.h>

#define TEMP_INV 20.0f
#define BATCH    1024
#define NSAMP    100000
#define NFEAT    256
#define BM       128
#define BN       128
#define BK       64
#define NCH      ((NSAMP + BN - 1) / BN)   /* 782 */
#define NCH_PAD  784                        /* 8 * 98 */

typedef __bf16 bf16x8 __attribute__((ext_vector_type(8)));
typedef float  f32x4  __attribute__((ext_vector_type(4)));

#define NEG_SENTINEL (-1e30f)

// async global->LDS, 16B per lane; LDS dest = wave-uniform base + lane*16
#define GLOAD_LDS16(g, l) __builtin_amdgcn_global_load_lds(               \
    (const __attribute__((address_space(1))) void*)(g),                   \
    (__attribute__((address_space(3))) void*)(l), 16, 0, 0)

// ---------------------------------------------------------------------------
// Kernel 0: convert feats (+zero-pad to 100096 rows) and inputs to bf16.
// One unit = 8 elems. 4 units per thread, stride-256 units (coalesced),
// independent chains for ILP. 3160 blocks x 256 threads x 4 units.
// ---------------------------------------------------------------------------
#define FEAT_UNITS     3203072
#define FEAT_SRC_UNITS 3200000
#define CVT_UNITS      3235840   /* = 3160 * 1024 */
__global__ __launch_bounds__(256) void convert_kernel(
    const float* __restrict__ feats, const float* __restrict__ inputs,
    __bf16* __restrict__ fb, __bf16* __restrict__ ib)
{
    size_t u0 = (size_t)blockIdx.x * 1024 + threadIdx.x;
    #pragma unroll
    for (int i = 0; i < 4; i++) {
        size_t u = u0 + i * 256;
        const float* src;
        __bf16* dst;
        bool zero = false;
        if (u < FEAT_UNITS) {
            dst = fb + u * 8;
            src = feats + u * 8;
            if (u >= FEAT_SRC_UNITS) zero = true;
        } else {
            size_t v = u - FEAT_UNITS;
            dst = ib + v * 8;
            src = inputs + v * 8;
        }
        bf16x8 o;
        if (!zero) {
            float4 a = ((const float4*)src)[0];
            float4 b = ((const float4*)src)[1];
            o[0] = (__bf16)a.x; o[1] = (__bf16)a.y; o[2] = (__bf16)a.z; o[3] = (__bf16)a.w;
            o[4] = (__bf16)b.x; o[5] = (__bf16)b.y; o[6] = (__bf16)b.z; o[7] = (__bf16)b.w;
        } else {
            #pragma unroll
            for (int q = 0; q < 8; q++) o[q] = (__bf16)0.0f;
        }
        *(bf16x8*)dst = o;
    }
}

// ---------------------------------------------------------------------------
// Kernel 1: per-row target logit in full fp32. One wave per row.
// ---------------------------------------------------------------------------
__global__ __launch_bounds__(256) void target_kernel(
    const float* __restrict__ inputs, const int* __restrict__ targets,
    const float* __restrict__ feats, float* __restrict__ tlogit)
{
    int lane = threadIdx.x & 63;
    int wid  = threadIdx.x >> 6;
    int row  = blockIdx.x * 4 + wid;
    int tgt  = targets[row];
    const float4* a = (const float4*)(inputs + (size_t)row * NFEAT);
    const float4* f = (const float4*)(feats  + (size_t)tgt * NFEAT);
    float4 av = a[lane];
    float4 fv = f[lane];
    float d = av.x * fv.x + av.y * fv.y + av.z * fv.z + av.w * fv.w;
    #pragma unroll
    for (int off = 1; off < 64; off <<= 1)
        d += __shfl_xor(d, off, 64);
    if (lane == 0) tlogit[row] = d * TEMP_INV;
}

// ---------------------------------------------------------------------------
// Kernel 2: one-barrier bf16 MFMA GEMM + per-chunk online-softmax partials.
// 128x128 tile, full K=256 staged at once. 4 waves, wave w = rows w*32..+32,
// all 128 cols (4x1 layout -> every output row lives in one wave).
// A: preloaded to registers in MFMA A-frag layout (16 bf16x8 = 64 VGPRs).
// B: full 64 KB in LDS as 4 swizzled BK=64 slabs via global_load_lds w=16.
// ---------------------------------------------------------------------------
__global__ __launch_bounds__(256, 2) void gemm_softmax_kernel(
    const __bf16* __restrict__ A, const __bf16* __restrict__ B,
    float2* __restrict__ partials)
{
    int L  = blockIdx.x;
    int j  = L & 7;                 // XCD id (round-robin)
    int t  = L >> 3;
    int mx = t & 7;                 // m-tile sweeps fastest -> B-chunk L2 reuse
    int ny = (t >> 3) * 8 + j;
    if (ny >= NCH) return;
    int m0 = mx * BM;
    int n0 = ny * BN;

    __shared__ __bf16 Blds[4][BN][BK];   // 64 KB, slab k0: chunk pos p = kc ^ (row&7)

    int tid  = threadIdx.x;
    int lane = tid & 63;
    int w    = tid >> 6;
    int lrow = lane & 15;
    int quad = lane >> 4;

    // ---- A preload: wave w rows m0+w*32..+32, full K, A-frag layout ----
    bf16x8 Areg[16];                // [k0*4 + ks*2 + mi]
    const __bf16* Abase = A + (size_t)(m0 + w * 32 + lrow) * NFEAT + quad * 8;
    #pragma unroll
    for (int k0 = 0; k0 < 4; k0++)
        #pragma unroll
        for (int ks = 0; ks < 2; ks++)
            #pragma unroll
            for (int mi = 0; mi < 2; mi++)
                Areg[k0 * 4 + ks * 2 + mi] =
                    *(const bf16x8*)(Abase + (size_t)mi * 16 * NFEAT + k0 * 64 + ks * 32);

    // ---- B stage: all 4 slabs, 16 global_load_lds per wave, ONE barrier ----
    int rowoff = lane >> 3;         // 0..7
    int p      = lane & 7;          // swizzled chunk position
    int kc     = p ^ rowoff;        // global 16B-chunk index within slab
    const __bf16* Bg = B + (size_t)(n0 + w * 32 + rowoff) * NFEAT + kc * 8;
    #pragma unroll
    for (int k0 = 0; k0 < 4; k0++)
        #pragma unroll
        for (int i = 0; i < 4; i++)
            GLOAD_LDS16(Bg + k0 * 64 + (size_t)i * 8 * NFEAT,
                        &Blds[k0][w * 32 + i * 8][0]);
    __syncthreads();                // the only barrier

    // ---- compute: 128 MFMA + 64 ds_read_b128, fully unrolled ----
    f32x4 acc[2][8] = {};
    #pragma unroll
    for (int k0 = 0; k0 < 4; k0++) {
        #pragma unroll
        for (int ks = 0; ks < 2; ks++) {
            bf16x8 bfr[8];
            #pragma unroll
            for (int ni = 0; ni < 8; ni++) {
                int R = ni * 16 + lrow;
                bfr[ni] = *(bf16x8*)&Blds[k0][R][((ks * 4 + quad) ^ (R & 7)) * 8];
            }
            #pragma unroll
            for (int mi = 0; mi < 2; mi++)
                #pragma unroll
                for (int ni = 0; ni < 8; ni++)
                    acc[mi][ni] = __builtin_amdgcn_mfma_f32_16x16x32_bf16(
                        Areg[k0 * 4 + ks * 2 + mi], bfr[ni], acc[mi][ni], 0, 0, 0);
        }
    }

    // ---- epilogue: per-row (m, s); rows fully inside this wave ----
    // C layout: row = quad*4 + reg, col = lane&15 per 16x16 tile
    bool ok[8];
    #pragma unroll
    for (int ni = 0; ni < 8; ni++) ok[ni] = (n0 + ni * 16 + lrow) < NSAMP;
    #pragma unroll
    for (int mi = 0; mi < 2; mi++) {
        #pragma unroll
        for (int reg = 0; reg < 4; reg++) {
            float v[8];
            #pragma unroll
            for (int ni = 0; ni < 8; ni++)
                v[ni] = ok[ni] ? acc[mi][ni][reg] * TEMP_INV : NEG_SENTINEL;
            float m = v[0];
            #pragma unroll
            for (int ni = 1; ni < 8; ni++) m = fmaxf(m, v[ni]);
            #pragma unroll
            for (int off = 1; off < 16; off <<= 1)
                m = fmaxf(m, __shfl_xor(m, off, 64));
            float s = 0.f;
            #pragma unroll
            for (int ni = 0; ni < 8; ni++) s += __expf(v[ni] - m);
            #pragma unroll
            for (int off = 1; off < 16; off <<= 1)
                s += __shfl_xor(s, off, 64);
            if (lrow == 0)
                partials[(size_t)ny * BATCH +
                         (m0 + w * 32 + mi * 16 + quad * 4 + reg)] = make_float2(m, s);
        }
    }
}

// ---------------------------------------------------------------------------
// Kernel 3: combine per-chunk partials -> lse -> nll -> mean (atomicAdd).
// ---------------------------------------------------------------------------
__global__ __launch_bounds__(256) void reduce_kernel(
    const float2* __restrict__ partials, const float* __restrict__ tlogit,
    float* __restrict__ out)
{
    __shared__ float2 red2[8][32];
    int tid = threadIdx.x;
    int rl  = tid & 31;
    int sp  = tid >> 5;
    int row = blockIdx.x * 32 + rl;
    int cs  = sp * 98;
    int ce  = cs + 98 < NCH ? cs + 98 : NCH;
    float m = NEG_SENTINEL, s = 0.f;
    #pragma unroll 4
    for (int c = cs; c < ce; c++) {
        float2 pt = partials[(size_t)c * BATCH + row];
        float nm = fmaxf(m, pt.x);
        s = s * __expf(m - nm) + pt.y * __expf(pt.x - nm);
        m = nm;
    }
    red2[sp][rl] = make_float2(m, s);
    __syncthreads();
    if (tid < 32) {
        float2 a = red2[0][rl];
        float M = a.x, S = a.y;
        #pragma unroll
        for (int q = 1; q < 8; q++) {
            float2 b = red2[q][rl];
            float nm = fmaxf(M, b.x);
            S = S * __expf(M - nm) + b.y * __expf(b.x - nm);
            M = nm;
        }
        float nll = (M + logf(S)) - tlogit[row];
        #pragma unroll
        for (int off = 1; off < 32; off <<= 1)
            nll += __shfl_xor(nll, off, 64);
        if (rl == 0) atomicAdd(out, nll * (1.0f / BATCH));
    }
}

// ---------------------------------------------------------------------------
extern "C" void kernel_launch(void* const* d_in, const int* in_sizes, int n_in,
                              void* d_out, int out_size, void* d_ws, size_t ws_size,
                              hipStream_t stream) {
    const float* inputs  = (const float*)d_in[0];
    const int*   targets = (const int*)d_in[1];
    const float* feats   = (const float*)d_in[2];
    float* out = (float*)d_out;

    // ws layout (bytes):
    //   fb       : 0          .. 51,249,152   (100096*256 bf16)
    //   ib       : 51,249,152 .. 51,773,440   (1024*256 bf16)
    //   partials : 51,773,440 .. 58,179,584   (782*1024 float2)
    //   tlogit   : 58,179,584 .. +4096
    __bf16* fb       = (__bf16*)d_ws;
    __bf16* ib       = (__bf16*)((char*)d_ws + 51249152);
    float2* partials = (float2*)((char*)d_ws + 51773440);
    float*  tlogit   = (float*)((char*)d_ws + 58179584);

    hipMemsetAsync(out, 0, sizeof(float), stream);
    convert_kernel<<<CVT_UNITS / 1024, 256, 0, stream>>>(feats, inputs, fb, ib);
    target_kernel<<<BATCH / 4, 256, 0, stream>>>(inputs, targets, feats, tlogit);
    gemm_softmax_kernel<<<8 * NCH_PAD, 256, 0, stream>>>(ib, fb, partials);
    reduce_kernel<<<BATCH / 32, 256, 0, stream>>>(partials, tlogit, out);
}